// Round 5
// baseline (682.978 us; speedup 1.0000x reference)
//
#include <hip/hip_runtime.h>

#define B_TREES 128
#define NPT 255
#define NTOT (B_TREES * NPT)   // 32640
#define FIN 64
#define HH 256

__device__ __forceinline__ float sigf(float x) {
    return __frcp_rn(1.0f + __expf(-x));
}
__device__ __forceinline__ float tanh_fast(float x) {
    return __builtin_fmaf(2.0f, sigf(2.0f * x), -1.0f);
}

// ---------------------------------------------------------------------------
// Transposed weight layout, float4-friendly:
//   (float4*)WT  + k4*1024 + col  = {M[col][4k4..4k4+3]}, M = [Uiou; Uf]
//   (float4*)WxT + k4*1024 + col  = same for [Wiou; 2*Wf]  (x2 fold for fs)
// ---------------------------------------------------------------------------
__global__ __launch_bounds__(256) void transpose_weights(
    const float* __restrict__ Uiou, const float* __restrict__ Uf,
    const float* __restrict__ Wiou, const float* __restrict__ Wf,
    float* __restrict__ WT, float* __restrict__ WxT)
{
    int idx = blockIdx.x * 256 + threadIdx.x;
    if (idx < 256 * 1024) {
        int k = idx >> 10, j = idx & 1023;
        float v = (j < 768) ? Uiou[(size_t)j * 256 + k] : Uf[(size_t)(j - 768) * 256 + k];
        WT[(size_t)(k >> 2) * 4096 + j * 4 + (k & 3)] = v;
    } else {
        int idx2 = idx - 256 * 1024;   // < 64*1024 by grid construction
        int k = idx2 >> 10, j = idx2 & 1023;
        float v = (j < 768) ? Wiou[(size_t)j * 64 + k] : 2.0f * Wf[(size_t)(j - 768) * 64 + k];
        WxT[(size_t)(k >> 2) * 4096 + j * 4 + (k & 3)] = v;
    }
}

// ---------------------------------------------------------------------------
// Leaves: iou = W_iou x + b; c = sig(i)*tanh(u); h = sig(o)*tanh(c).
// 16 leaves / block, 1024 blocks x 256 threads (4 blocks/CU).
// ---------------------------------------------------------------------------
template<bool TR>
__global__ __launch_bounds__(256) void leaf_v2(
    const float* __restrict__ feat,
    const float* __restrict__ WxT, const float* __restrict__ Wiou,
    const float* __restrict__ biou,
    float* __restrict__ h, float* __restrict__ c)
{
    const int NB = 16;
    __shared__ float xs[NB][FIN];
    int tid = threadIdx.x;
    int l0 = blockIdx.x * NB;
    int b = l0 >> 7;
    int g0 = b * NPT + 127 + (l0 & 127);
    const float* fb = feat + (size_t)g0 * FIN;
    for (int i = tid; i < NB * FIN; i += 256) ((float*)xs)[i] = fb[i];
    __syncthreads();

    float ai[NB], ao[NB], au[NB];
#pragma unroll
    for (int n = 0; n < NB; ++n) { ai[n] = 0.f; ao[n] = 0.f; au[n] = 0.f; }

    const float4* WxT4 = (const float4*)WxT;
    for (int k4 = 0; k4 < 16; ++k4) {
        float4 wi, wo, wu;
        if constexpr (TR) {
            size_t base = (size_t)k4 * 1024 + tid;
            wi = WxT4[base]; wo = WxT4[base + 256]; wu = WxT4[base + 512];
        } else {
            wi = *(const float4*)(Wiou + (size_t)tid * FIN + 4 * k4);
            wo = *(const float4*)(Wiou + (size_t)(tid + 256) * FIN + 4 * k4);
            wu = *(const float4*)(Wiou + (size_t)(tid + 512) * FIN + 4 * k4);
        }
#pragma unroll
        for (int n = 0; n < NB; ++n) {
            float4 x4 = ((const float4*)xs[n])[k4];
            ai[n] += wi.x * x4.x + wi.y * x4.y + wi.z * x4.z + wi.w * x4.w;
            ao[n] += wo.x * x4.x + wo.y * x4.y + wo.z * x4.z + wo.w * x4.w;
            au[n] += wu.x * x4.x + wu.y * x4.y + wu.z * x4.z + wu.w * x4.w;
        }
    }

    float bi = biou[tid], bo = biou[tid + 256], bu = biou[tid + 512];
#pragma unroll
    for (int n = 0; n < NB; ++n) {
        float iv = sigf(ai[n] + bi);
        float ov = sigf(ao[n] + bo);
        float uv = tanh_fast(au[n] + bu);
        float cv = iv * uv;
        float hv = ov * tanh_fast(cv);
        c[(size_t)(g0 + n) * HH + tid] = cv;
        h[(size_t)(g0 + n) * HH + tid] = hv;
    }
}

// ---------------------------------------------------------------------------
// Wide internal level kernel: 1024 threads, 8 nodes/block, NN=2 nodes/thread.
// Thread (g = tid>>8, j = tid&255): output columns {j,+256,+512,+768} of
// nodes {g, g+4}. 10 accumulators + 16 weight regs fits the 64-VGPR budget
// the compiler assigns 1024-thread blocks (2 blocks/CU, 8 waves/SIMD) -- the
// R3/R4 spills came from NN=4 variants blowing this budget.
// LDS hs/hd reads are wave-broadcast (address independent of lane).
// ---------------------------------------------------------------------------
template<bool TR>
__global__ __launch_bounds__(1024) void wide_internal(
    const float* __restrict__ feat,
    const float* __restrict__ WT, const float* __restrict__ WxT,
    const float* __restrict__ Uiou, const float* __restrict__ Uf,
    const float* __restrict__ Wiou, const float* __restrict__ Wf,
    const float* __restrict__ biou, const float* __restrict__ bfv,
    float* __restrict__ h, float* __restrict__ c,
    int Lt, int lg)
{
    __shared__ float hs[8][HH], hd[8][HH];
    __shared__ float xs[8][FIN];
    const int tid = threadIdx.x;
    const int j = tid & 255, g = tid >> 8;
    int m0 = blockIdx.x * 8;
    int b = m0 >> lg;
    int ii0 = Lt + (m0 & ((1 << lg) - 1));
    int g0 = b * NPT + ii0;
    int gc0 = g0 + ii0 + 1;            // first child row of node 0

    for (int i = tid; i < 8 * HH; i += 1024) {
        int n = i >> 8, k = i & 255;
        float a  = h[(size_t)(gc0 + 2 * n) * HH + k];
        float bb = h[(size_t)(gc0 + 2 * n + 1) * HH + k];
        hs[n][k] = a + bb;
        hd[n][k] = a - bb;
    }
    for (int i = tid; i < 8 * FIN; i += 1024)
        ((float*)xs)[i] = feat[(size_t)g0 * FIN + i];
    __syncthreads();

    float ai[2] = {0.f, 0.f}, ao[2] = {0.f, 0.f}, au[2] = {0.f, 0.f};
    float fs[2] = {0.f, 0.f}, fd[2] = {0.f, 0.f};

    const float4* WT4  = (const float4*)WT;
    const float4* WxT4 = (const float4*)WxT;
    for (int k4 = 0; k4 < 64; ++k4) {
        float4 wi, wo, wu, wf;
        if constexpr (TR) {
            size_t base = (size_t)k4 * 1024 + j;
            wi = WT4[base];
            wo = WT4[base + 256];
            wu = WT4[base + 512];
            wf = WT4[base + 768];
        } else {
            wi = *(const float4*)(Uiou + (size_t)j * HH + 4 * k4);
            wo = *(const float4*)(Uiou + (size_t)(j + 256) * HH + 4 * k4);
            wu = *(const float4*)(Uiou + (size_t)(j + 512) * HH + 4 * k4);
            wf = *(const float4*)(Uf + (size_t)j * HH + 4 * k4);
        }
#pragma unroll
        for (int q = 0; q < 2; ++q) {
            int n = g + 4 * q;
            float4 s4 = ((const float4*)hs[n])[k4];
            float4 d4 = ((const float4*)hd[n])[k4];
            ai[q] += wi.x * s4.x + wi.y * s4.y + wi.z * s4.z + wi.w * s4.w;
            ao[q] += wo.x * s4.x + wo.y * s4.y + wo.z * s4.z + wo.w * s4.w;
            au[q] += wu.x * s4.x + wu.y * s4.y + wu.z * s4.z + wu.w * s4.w;
            fs[q] += wf.x * s4.x + wf.y * s4.y + wf.z * s4.z + wf.w * s4.w;
            fd[q] += wf.x * d4.x + wf.y * d4.y + wf.z * d4.z + wf.w * d4.w;
        }
    }
    for (int k4 = 0; k4 < 16; ++k4) {
        float4 wi, wo, wu, wf;
        if constexpr (TR) {
            size_t base = (size_t)k4 * 1024 + j;
            wi = WxT4[base];
            wo = WxT4[base + 256];
            wu = WxT4[base + 512];
            wf = WxT4[base + 768];
        } else {
            wi = *(const float4*)(Wiou + (size_t)j * FIN + 4 * k4);
            wo = *(const float4*)(Wiou + (size_t)(j + 256) * FIN + 4 * k4);
            wu = *(const float4*)(Wiou + (size_t)(j + 512) * FIN + 4 * k4);
            float4 t3 = *(const float4*)(Wf + (size_t)j * FIN + 4 * k4);
            wf.x = 2.0f * t3.x; wf.y = 2.0f * t3.y; wf.z = 2.0f * t3.z; wf.w = 2.0f * t3.w;
        }
#pragma unroll
        for (int q = 0; q < 2; ++q) {
            int n = g + 4 * q;
            float4 x4 = ((const float4*)xs[n])[k4];
            ai[q] += wi.x * x4.x + wi.y * x4.y + wi.z * x4.z + wi.w * x4.w;
            ao[q] += wo.x * x4.x + wo.y * x4.y + wo.z * x4.z + wo.w * x4.w;
            au[q] += wu.x * x4.x + wu.y * x4.y + wu.z * x4.z + wu.w * x4.w;
            fs[q] += wf.x * x4.x + wf.y * x4.y + wf.z * x4.z + wf.w * x4.w;
        }
    }

    float bi = biou[j], bo = biou[j + 256], bu = biou[j + 512], bF = bfv[j];
#pragma unroll
    for (int q = 0; q < 2; ++q) {
        int n = g + 4 * q;
        float iv = sigf(ai[q] + bi);
        float ov = sigf(ao[q] + bo);
        float uv = tanh_fast(au[q] + bu);
        float f1 = sigf(0.5f * (fs[q] + fd[q]) + bF);
        float f2 = sigf(0.5f * (fs[q] - fd[q]) + bF);
        float c1 = c[(size_t)(gc0 + 2 * n) * HH + j];
        float c2 = c[(size_t)(gc0 + 2 * n + 1) * HH + j];
        float cv = iv * uv + f1 * c1 + f2 * c2;
        float hv = ov * tanh_fast(cv);
        c[(size_t)(g0 + n) * HH + j] = cv;
        h[(size_t)(g0 + n) * HH + j] = hv;
    }
}

// ---------------------------------------------------------------------------
// Merged tail: levels nt = 8,4,2,1 (local nodes 14..0), one 1024-thread block
// per tree. NN = 2 (nt=8) or 1 -> no spill at 64 VGPR. h/c of nodes 0..14
// kept in LDS between levels; first level's children (15..30) from global.
// ---------------------------------------------------------------------------
template<int NT, bool FIRST, bool TR>
__device__ void tts_level(
    int gb, const float* __restrict__ feat,
    const float* __restrict__ WT, const float* __restrict__ WxT,
    const float* __restrict__ Uiou, const float* __restrict__ Uf,
    const float* __restrict__ Wiou, const float* __restrict__ Wf,
    const float* __restrict__ biou, const float* __restrict__ bfv,
    float* __restrict__ h, float* __restrict__ c,
    float (*hl)[HH], float (*cl)[HH],
    float (*hs)[HH], float (*hd)[HH], float (*xs)[FIN])
{
    const int tid = threadIdx.x;
    const int j = tid & 255, g = tid >> 8;
    const int first = NT - 1;
    constexpr int NN = (NT == 8) ? 2 : 1;
    const bool act = (NT >= 4) || (g < NT);

    for (int i = tid; i < NT * HH; i += 1024) {
        int n = i >> 8, k = i & 255;
        int ch = 2 * (first + n) + 1;
        float a, bb;
        if constexpr (FIRST) {
            a  = h[(size_t)(gb + ch) * HH + k];
            bb = h[(size_t)(gb + ch + 1) * HH + k];
        } else {
            a  = hl[ch][k];
            bb = hl[ch + 1][k];
        }
        hs[n][k] = a + bb;
        hd[n][k] = a - bb;
    }
    for (int i = tid; i < NT * FIN; i += 1024)
        ((float*)xs)[i] = feat[(size_t)(gb + first) * FIN + i];
    __syncthreads();

    float ai[NN], ao[NN], au[NN], fs[NN], fd[NN];
#pragma unroll
    for (int q = 0; q < NN; ++q) { ai[q] = 0.f; ao[q] = 0.f; au[q] = 0.f; fs[q] = 0.f; fd[q] = 0.f; }

    if (act) {
        const float4* WT4  = (const float4*)WT;
        const float4* WxT4 = (const float4*)WxT;
        for (int k4 = 0; k4 < 64; ++k4) {
            float4 wi, wo, wu, wf;
            if constexpr (TR) {
                size_t base = (size_t)k4 * 1024 + j;
                wi = WT4[base];
                wo = WT4[base + 256];
                wu = WT4[base + 512];
                wf = WT4[base + 768];
            } else {
                wi = *(const float4*)(Uiou + (size_t)j * HH + 4 * k4);
                wo = *(const float4*)(Uiou + (size_t)(j + 256) * HH + 4 * k4);
                wu = *(const float4*)(Uiou + (size_t)(j + 512) * HH + 4 * k4);
                wf = *(const float4*)(Uf + (size_t)j * HH + 4 * k4);
            }
#pragma unroll
            for (int q = 0; q < NN; ++q) {
                int n = (NT == 8) ? (g + 4 * q) : g;
                float4 s4 = ((const float4*)hs[n])[k4];
                float4 d4 = ((const float4*)hd[n])[k4];
                ai[q] += wi.x * s4.x + wi.y * s4.y + wi.z * s4.z + wi.w * s4.w;
                ao[q] += wo.x * s4.x + wo.y * s4.y + wo.z * s4.z + wo.w * s4.w;
                au[q] += wu.x * s4.x + wu.y * s4.y + wu.z * s4.z + wu.w * s4.w;
                fs[q] += wf.x * s4.x + wf.y * s4.y + wf.z * s4.z + wf.w * s4.w;
                fd[q] += wf.x * d4.x + wf.y * d4.y + wf.z * d4.z + wf.w * d4.w;
            }
        }
        for (int k4 = 0; k4 < 16; ++k4) {
            float4 wi, wo, wu, wf;
            if constexpr (TR) {
                size_t base = (size_t)k4 * 1024 + j;
                wi = WxT4[base];
                wo = WxT4[base + 256];
                wu = WxT4[base + 512];
                wf = WxT4[base + 768];
            } else {
                wi = *(const float4*)(Wiou + (size_t)j * FIN + 4 * k4);
                wo = *(const float4*)(Wiou + (size_t)(j + 256) * FIN + 4 * k4);
                wu = *(const float4*)(Wiou + (size_t)(j + 512) * FIN + 4 * k4);
                float4 t3 = *(const float4*)(Wf + (size_t)j * FIN + 4 * k4);
                wf.x = 2.0f * t3.x; wf.y = 2.0f * t3.y; wf.z = 2.0f * t3.z; wf.w = 2.0f * t3.w;
            }
#pragma unroll
            for (int q = 0; q < NN; ++q) {
                int n = (NT == 8) ? (g + 4 * q) : g;
                float4 x4 = ((const float4*)xs[n])[k4];
                ai[q] += wi.x * x4.x + wi.y * x4.y + wi.z * x4.z + wi.w * x4.w;
                ao[q] += wo.x * x4.x + wo.y * x4.y + wo.z * x4.z + wo.w * x4.w;
                au[q] += wu.x * x4.x + wu.y * x4.y + wu.z * x4.z + wu.w * x4.w;
                fs[q] += wf.x * x4.x + wf.y * x4.y + wf.z * x4.z + wf.w * x4.w;
            }
        }

        float bi = biou[j], bo = biou[j + 256], bu = biou[j + 512], bF = bfv[j];
#pragma unroll
        for (int q = 0; q < NN; ++q) {
            int n = (NT == 8) ? (g + 4 * q) : g;
            int node = first + n;
            int ch = 2 * node + 1;
            float iv = sigf(ai[q] + bi);
            float ov = sigf(ao[q] + bo);
            float uv = tanh_fast(au[q] + bu);
            float f1 = sigf(0.5f * (fs[q] + fd[q]) + bF);
            float f2 = sigf(0.5f * (fs[q] - fd[q]) + bF);
            float c1, c2;
            if constexpr (FIRST) {
                c1 = c[(size_t)(gb + ch) * HH + j];
                c2 = c[(size_t)(gb + ch + 1) * HH + j];
            } else {
                c1 = cl[ch][j];
                c2 = cl[ch + 1][j];
            }
            float cv = iv * uv + f1 * c1 + f2 * c2;
            float hv = ov * tanh_fast(cv);
            hl[node][j] = hv;
            cl[node][j] = cv;
            h[(size_t)(gb + node) * HH + j] = hv;
            c[(size_t)(gb + node) * HH + j] = cv;
        }
    }
    __syncthreads();
}

template<bool TR>
__global__ __launch_bounds__(1024) void tree_tail(
    const float* __restrict__ feat,
    const float* __restrict__ WT, const float* __restrict__ WxT,
    const float* __restrict__ Uiou, const float* __restrict__ Uf,
    const float* __restrict__ Wiou, const float* __restrict__ Wf,
    const float* __restrict__ biou, const float* __restrict__ bfv,
    float* __restrict__ h, float* __restrict__ c)
{
    __shared__ float hl[15][HH], cl[15][HH];
    __shared__ float hs[8][HH], hd[8][HH];
    __shared__ float xs[8][FIN];
    int gb = blockIdx.x * NPT;
    tts_level<8, true,  TR>(gb, feat, WT, WxT, Uiou, Uf, Wiou, Wf, biou, bfv, h, c, hl, cl, hs, hd, xs);
    tts_level<4, false, TR>(gb, feat, WT, WxT, Uiou, Uf, Wiou, Wf, biou, bfv, h, c, hl, cl, hs, hd, xs);
    tts_level<2, false, TR>(gb, feat, WT, WxT, Uiou, Uf, Wiou, Wf, biou, bfv, h, c, hl, cl, hs, hd, xs);
    tts_level<1, false, TR>(gb, feat, WT, WxT, Uiou, Uf, Wiou, Wf, biou, bfv, h, c, hl, cl, hs, hd, xs);
}

// ---------------------------------------------------------------------------
// Head, WIDE: 1024 threads/tree. g-groups split the 255-node mean 4-way and
// the lin0 K-reduction 4-way; final lin1 dot on g==0 waves.
// ---------------------------------------------------------------------------
__global__ __launch_bounds__(1024) void head_wide(
    const float* __restrict__ h,
    const float* __restrict__ l0w, const float* __restrict__ l0b,
    const float* __restrict__ l1w, const float* __restrict__ l1b,
    float* __restrict__ out)
{
    __shared__ float ms[4][HH];
    __shared__ float part[4][HH];
    __shared__ float red[4];
    int b = blockIdx.x, tid = threadIdx.x;
    int j = tid & 255, g = tid >> 8;
    const float* hb = h + (size_t)b * NPT * HH;

    float a = 0.f;
    for (int i = g; i < NPT; i += 4) a += hb[(size_t)i * HH + j];
    ms[g][j] = a;
    __syncthreads();
    if (g == 0) ms[0][j] = (ms[0][j] + ms[1][j] + ms[2][j] + ms[3][j]) * (1.0f / (float)NPT);
    __syncthreads();

    const float4* L0 = (const float4*)(l0w + (size_t)j * HH);
    float y = 0.f;
    for (int k4 = 16 * g; k4 < 16 * (g + 1); ++k4) {
        float4 w = L0[k4];
        float4 m4 = ((const float4*)ms[0])[k4];
        y += w.x * m4.x + w.y * m4.y + w.z * m4.z + w.w * m4.w;
    }
    part[g][j] = y;
    __syncthreads();

    if (g == 0) {
        float yy = part[0][j] + part[1][j] + part[2][j] + part[3][j] + l0b[j];
        yy = fmaxf(yy, 0.f);
        float v = yy * l1w[j];
        for (int off = 32; off > 0; off >>= 1) v += __shfl_down(v, off, 64);
        if ((j & 63) == 0) red[j >> 6] = v;
    }
    __syncthreads();
    if (tid == 0) out[b] = red[0] + red[1] + red[2] + red[3] + l1b[0];
}

// ---------------------------------------------------------------------------
extern "C" void kernel_launch(void* const* d_in, const int* in_sizes, int n_in,
                              void* d_out, int out_size, void* d_ws, size_t ws_size,
                              hipStream_t stream)
{
    const float* feat = (const float*)d_in[0];
    const float* Wiou = (const float*)d_in[4];
    const float* biou = (const float*)d_in[5];
    const float* Uiou = (const float*)d_in[6];
    const float* Wf   = (const float*)d_in[7];
    const float* bfv  = (const float*)d_in[8];
    const float* Uf   = (const float*)d_in[9];
    const float* l0w  = (const float*)d_in[10];
    const float* l0b  = (const float*)d_in[11];
    const float* l1w  = (const float*)d_in[12];
    const float* l1b  = (const float*)d_in[13];

    float* h  = (float*)d_ws;
    float* c  = h + (size_t)NTOT * HH;
    float* WT  = c + (size_t)NTOT * HH;
    float* WxT = WT + 256 * 1024;
    size_t need = ((size_t)NTOT * HH * 2 + 256 * 1024 + 64 * 1024) * sizeof(float);
    bool tr = (ws_size >= need);

    if (tr) {
        transpose_weights<<<1280, 256, 0, stream>>>(Uiou, Uf, Wiou, Wf, WT, WxT);
        leaf_v2<true><<<1024, 256, 0, stream>>>(feat, WxT, Wiou, biou, h, c);
        // t=1: 64 nodes/tree, M=8192 -> 1024 blocks
        wide_internal<true><<<1024, 1024, 0, stream>>>(feat, WT, WxT, Uiou, Uf, Wiou, Wf,
                                                       biou, bfv, h, c, 63, 6);
        // t=2: 32 nodes/tree, M=4096 -> 512 blocks
        wide_internal<true><<<512, 1024, 0, stream>>>(feat, WT, WxT, Uiou, Uf, Wiou, Wf,
                                                      biou, bfv, h, c, 31, 5);
        // t=3: 16 nodes/tree, M=2048 -> 256 blocks
        wide_internal<true><<<256, 1024, 0, stream>>>(feat, WT, WxT, Uiou, Uf, Wiou, Wf,
                                                      biou, bfv, h, c, 15, 4);
        // t=4..7 merged
        tree_tail<true><<<128, 1024, 0, stream>>>(feat, WT, WxT, Uiou, Uf, Wiou, Wf,
                                                  biou, bfv, h, c);
    } else {
        leaf_v2<false><<<1024, 256, 0, stream>>>(feat, WxT, Wiou, biou, h, c);
        wide_internal<false><<<1024, 1024, 0, stream>>>(feat, WT, WxT, Uiou, Uf, Wiou, Wf,
                                                        biou, bfv, h, c, 63, 6);
        wide_internal<false><<<512, 1024, 0, stream>>>(feat, WT, WxT, Uiou, Uf, Wiou, Wf,
                                                       biou, bfv, h, c, 31, 5);
        wide_internal<false><<<256, 1024, 0, stream>>>(feat, WT, WxT, Uiou, Uf, Wiou, Wf,
                                                       biou, bfv, h, c, 15, 4);
        tree_tail<false><<<128, 1024, 0, stream>>>(feat, WT, WxT, Uiou, Uf, Wiou, Wf,
                                                   biou, bfv, h, c);
    }
    head_wide<<<B_TREES, 1024, 0, stream>>>(h, l0w, l0b, l1w, l1b, (float*)d_out);
}

// Round 6
// 280.758 us; speedup vs baseline: 2.4326x; 2.4326x over previous
//
#include <hip/hip_runtime.h>

#define B_TREES 128
#define NPT 255
#define NTOT (B_TREES * NPT)   // 32640
#define FIN 64
#define HH 256

typedef short bf16x8 __attribute__((ext_vector_type(8)));
typedef float f32x4  __attribute__((ext_vector_type(4)));
typedef unsigned short u16;

__device__ __forceinline__ float sigf(float x) {
    return __frcp_rn(1.0f + __expf(-x));
}
__device__ __forceinline__ float tanh_fast(float x) {
    return __builtin_fmaf(2.0f, sigf(2.0f * x), -1.0f);
}
__device__ __forceinline__ u16 bf_hi(float v) {       // round-to-nearest-even bf16
    unsigned u = __float_as_uint(v);
    return (u16)((u + 0x7FFFu + ((u >> 16) & 1u)) >> 16);
}
__device__ __forceinline__ float bf_f(u16 b) { return __uint_as_float(((unsigned)b) << 16); }

// ---------------------------------------------------------------------------
// B pack: B[576 x 1280] in MFMA-B-frag layout, split into bf16 hi + lo.
// Column c = hb*80 + s*16 + jl  (hb = hidden block of 16, s = stream, jl in [0,16))
//   s=0/1/2: i/o/u gates; s=3: fs; s=4: fd.
// col-tile ct = hb*5 + s.  k-ranges: s<4 -> k = ksl*32 + ...  (K=[0,320):
//   k<256: U rows (Uiou / Uf); 256<=k<320: W rows (Wiou / 2*Wf));
//   s=4 -> k = 320 + ksl*32 + ... (Uf rows vs hd; ksl>=8 slots are dead pad).
// Storage: elem index = ((ct*10 + ksl)*64 + lane)*8 + j ;
//   lane = (col&15) + 16*q, frag element k_local = q*8 + j.
// ---------------------------------------------------------------------------
__global__ __launch_bounds__(256) void pack_B(
    const float* __restrict__ Uiou, const float* __restrict__ Uf,
    const float* __restrict__ Wiou, const float* __restrict__ Wf,
    u16* __restrict__ Bhi, u16* __restrict__ Blo)
{
    int idx = blockIdx.x * 256 + threadIdx.x;   // < 80*10*64*8 = 409600
    int j    = idx & 7;
    int lane = (idx >> 3) & 63;
    int ksl  = (idx >> 9) % 10;
    int ct   = idx / 5120;
    int s = ct % 5, hb = ct / 5;
    int n = lane & 15, q = lane >> 4;
    int jH = hb * 16 + n;
    int k = (s < 4 ? ksl * 32 : 320 + ksl * 32) + q * 8 + j;

    float v = 0.0f;
    if (s == 4) {
        if (k < 576) v = Uf[(size_t)jH * HH + (k - 320)];
    } else {
        if (k < 256) {
            v = (s < 3) ? Uiou[(size_t)(s * 256 + jH) * HH + k]
                        : Uf[(size_t)jH * HH + k];
        } else {
            int kw = k - 256;
            v = (s < 3) ? Wiou[(size_t)(s * 256 + jH) * FIN + kw]
                        : 2.0f * Wf[(size_t)jH * FIN + kw];
        }
    }
    u16 hi = bf_hi(v);
    u16 lo = bf_hi(v - bf_f(hi));
    Bhi[idx] = hi;
    Blo[idx] = lo;
}

// ---------------------------------------------------------------------------
// Level kernel (MFMA, split-bf16). 256 threads = 4 waves, MB = 32 nodes/block.
// Grid = rowblocks * CSPLIT;  CSPLIT = 20/NCT (cols split across blocks).
// Wave w covers NCT col-tiles: ctbase = cs*4*NCT + w*NCT.
// A[32 x 576] = [hs | x | hd] staged in LDS in A-frag layout (hi & lo).
// K-loop: G=kstep 0..17; G<10 -> s<4 tiles; G>=10 -> s=4 tiles (local G-10).
// LEAF: hs=hd=0 -> only G in {8,9} (x rows), s=4 tiles stay 0, c1=c2=0.
// Epilogue: per-wave private (col interleave guarantees complete gate sets);
// C tiles -> per-wave LDS scratch (aliased over A after barrier) -> gates.
// ---------------------------------------------------------------------------
template<int NCT, bool LEAF>
__global__ __launch_bounds__(256, 2) void level_mfma(
    const float* __restrict__ feat,
    const u16* __restrict__ Bhi, const u16* __restrict__ Blo,
    const float* __restrict__ biou, const float* __restrict__ bfv,
    float* __restrict__ h, float* __restrict__ c,
    int Lt, int lg)
{
    constexpr int CSPLIT = 20 / NCT;
    constexpr int SUBS = NCT / 5;
    __shared__ char smem[73728];               // A_hi 36KB | A_lo 36KB ; aliased by epilogue scratch
    short* Ahi = (short*)smem;
    short* Alo = (short*)(smem + 36864);

    const int tid = threadIdx.x;
    const int lane = tid & 63, w = tid >> 6;
    const int cs = blockIdx.x % CSPLIT;
    const int rb = blockIdx.x / CSPLIT;
    const int m0 = rb * 32;
    const int msk = (1 << lg) - 1;
    const int ctbase = cs * 4 * NCT + w * NCT;

    const float4* Hf4 = (const float4*)h;
    const float4* Ff4 = (const float4*)feat;

    // ---- stage A ----
    if constexpr (!LEAF) {
        for (int rep = 0; rep < 8; ++rep) {            // hs/hd: 32 m x 64 float4
            int flat = rep * 256 + tid;
            int m = flat >> 6, f4 = flat & 63;
            int mg = m0 + m;
            int b = mg >> lg, ii = Lt + (mg & msk);
            int gc = b * NPT + 2 * ii + 1;
            float4 h1 = Hf4[(size_t)gc * 64 + f4];
            float4 h2 = Hf4[(size_t)(gc + 1) * 64 + f4];
            float hsv[4] = {h1.x + h2.x, h1.y + h2.y, h1.z + h2.z, h1.w + h2.w};
            float hdv[4] = {h1.x - h2.x, h1.y - h2.y, h1.z - h2.z, h1.w - h2.w};
            int rt = m >> 4, lm = m & 15;
            int ks = f4 >> 3;
            int lane_ = lm + 16 * ((f4 >> 1) & 3);
            int j0 = (f4 & 1) * 4;
            ushort4 sh, sl, dh, dl;
            u16* shp = (u16*)&sh; u16* slp = (u16*)&sl;
            u16* dhp = (u16*)&dh; u16* dlp = (u16*)&dl;
#pragma unroll
            for (int e = 0; e < 4; ++e) {
                u16 a = bf_hi(hsv[e]); shp[e] = a; slp[e] = bf_hi(hsv[e] - bf_f(a));
                u16 d = bf_hi(hdv[e]); dhp[e] = d; dlp[e] = bf_hi(hdv[e] - bf_f(d));
            }
            int base_s = ((rt * 18 + ks) * 64 + lane_) * 8 + j0;        // hs at kstep ks
            int base_d = ((rt * 18 + ks + 10) * 64 + lane_) * 8 + j0;   // hd at kstep ks+10
            *(ushort4*)&Ahi[base_s] = sh;  *(ushort4*)&Alo[base_s] = sl;
            *(ushort4*)&Ahi[base_d] = dh;  *(ushort4*)&Alo[base_d] = dl;
        }
    }
    for (int rep = 0; rep < 2; ++rep) {                // x: 32 m x 16 float4
        int flat = rep * 256 + tid;
        int m = flat >> 4, f4 = flat & 15;
        int mg = m0 + m;
        int b = mg >> lg, ii = Lt + (mg & msk);
        int g = b * NPT + ii;
        float4 x4 = Ff4[(size_t)g * 16 + f4];
        float xv[4] = {x4.x, x4.y, x4.z, x4.w};
        int rt = m >> 4, lm = m & 15;
        int ks = 8 + (f4 >> 3);
        int lane_ = lm + 16 * ((f4 >> 1) & 3);
        int j0 = (f4 & 1) * 4;
        ushort4 xh, xl;
        u16* xhp = (u16*)&xh; u16* xlp = (u16*)&xl;
#pragma unroll
        for (int e = 0; e < 4; ++e) {
            u16 a = bf_hi(xv[e]); xhp[e] = a; xlp[e] = bf_hi(xv[e] - bf_f(a));
        }
        int base = ((rt * 18 + ks) * 64 + lane_) * 8 + j0;
        *(ushort4*)&Ahi[base] = xh;  *(ushort4*)&Alo[base] = xl;
    }
    __syncthreads();

    // ---- K loop ----
    f32x4 acc[2][NCT];
#pragma unroll
    for (int rt = 0; rt < 2; ++rt)
#pragma unroll
        for (int i = 0; i < NCT; ++i) acc[rt][i] = (f32x4){0.f, 0.f, 0.f, 0.f};

    const int G0 = LEAF ? 8 : 0;
    for (int G = G0; G < 10; ++G) {                    // s<4 tiles
        bf16x8 ah[2], al[2];
#pragma unroll
        for (int rt = 0; rt < 2; ++rt) {
            ah[rt] = *(const bf16x8*)&Ahi[((rt * 18 + G) * 64 + lane) * 8];
            al[rt] = *(const bf16x8*)&Alo[((rt * 18 + G) * 64 + lane) * 8];
        }
#pragma unroll
        for (int ctl = 0; ctl < NCT; ++ctl) {
            if (ctl % 5 == 4) continue;
            size_t slot = (size_t)((ctbase + ctl) * 10 + G) * 512 + lane * 8;
            bf16x8 bh = *(const bf16x8*)(Bhi + slot);
            bf16x8 bl = *(const bf16x8*)(Blo + slot);
#pragma unroll
            for (int rt = 0; rt < 2; ++rt) {
                acc[rt][ctl] = __builtin_amdgcn_mfma_f32_16x16x32_bf16(ah[rt], bh, acc[rt][ctl], 0, 0, 0);
                acc[rt][ctl] = __builtin_amdgcn_mfma_f32_16x16x32_bf16(ah[rt], bl, acc[rt][ctl], 0, 0, 0);
                acc[rt][ctl] = __builtin_amdgcn_mfma_f32_16x16x32_bf16(al[rt], bh, acc[rt][ctl], 0, 0, 0);
            }
        }
    }
    if constexpr (!LEAF) {
        for (int G = 10; G < 18; ++G) {                // s=4 (fd) tiles, k in [320,576)
            bf16x8 ah[2], al[2];
#pragma unroll
            for (int rt = 0; rt < 2; ++rt) {
                ah[rt] = *(const bf16x8*)&Ahi[((rt * 18 + G) * 64 + lane) * 8];
                al[rt] = *(const bf16x8*)&Alo[((rt * 18 + G) * 64 + lane) * 8];
            }
#pragma unroll
            for (int ctl = 4; ctl < NCT; ctl += 5) {
                size_t slot = (size_t)((ctbase + ctl) * 10 + (G - 10)) * 512 + lane * 8;
                bf16x8 bh = *(const bf16x8*)(Bhi + slot);
                bf16x8 bl = *(const bf16x8*)(Blo + slot);
#pragma unroll
                for (int rt = 0; rt < 2; ++rt) {
                    acc[rt][ctl] = __builtin_amdgcn_mfma_f32_16x16x32_bf16(ah[rt], bh, acc[rt][ctl], 0, 0, 0);
                    acc[rt][ctl] = __builtin_amdgcn_mfma_f32_16x16x32_bf16(ah[rt], bl, acc[rt][ctl], 0, 0, 0);
                    acc[rt][ctl] = __builtin_amdgcn_mfma_f32_16x16x32_bf16(al[rt], bh, acc[rt][ctl], 0, 0, 0);
                }
            }
        }
    }
    __syncthreads();    // all waves done with A region; alias epilogue scratch over it

    // ---- epilogue (wave-private) ----
    float* sc = (float*)smem + w * 2592;       // [32 rows][81] fp32 per wave
    const int n = lane & 15, q = lane >> 4;
#pragma unroll
    for (int sub = 0; sub < SUBS; ++sub) {
        // write this sub's 2x5 C tiles to scratch
#pragma unroll
        for (int rt = 0; rt < 2; ++rt)
#pragma unroll
            for (int s = 0; s < 5; ++s) {
                f32x4 v = acc[rt][sub * 5 + s];
#pragma unroll
                for (int r = 0; r < 4; ++r)
                    sc[(rt * 16 + q * 4 + r) * 81 + s * 16 + n] = v[r];
            }
        int hb_abs = ctbase / 5 + sub;
        int jHb = hb_abs * 16;
        for (int it = 0; it < 8; ++it) {
            int idx = it * 64 + lane;           // 512 items: 32 m x 16 jl
            int m = idx >> 4, jl = idx & 15;
            int jH = jHb + jl;
            float Ci  = sc[m * 81 + jl];
            float Co  = sc[m * 81 + 16 + jl];
            float Cu  = sc[m * 81 + 32 + jl];
            float Cfs = sc[m * 81 + 48 + jl];
            float Cfd = sc[m * 81 + 64 + jl];
            int mg = m0 + m;
            int b = mg >> lg, ii = Lt + (mg & msk);
            size_t g = (size_t)b * NPT + ii;
            float iv = sigf(Ci + biou[jH]);
            float ov = sigf(Co + biou[256 + jH]);
            float uv = tanh_fast(Cu + biou[512 + jH]);
            float cv;
            if constexpr (LEAF) {
                cv = iv * uv;
            } else {
                size_t gc = g + ii + 1;         // b*NPT + 2*ii + 1
                float bF = bfv[jH];
                float f1 = sigf(0.5f * (Cfs + Cfd) + bF);
                float f2 = sigf(0.5f * (Cfs - Cfd) + bF);
                cv = iv * uv + f1 * c[gc * HH + jH] + f2 * c[(gc + 1) * HH + jH];
            }
            float hv = ov * tanh_fast(cv);
            c[g * HH + jH] = cv;
            h[g * HH + jH] = hv;
        }
    }
}

// ---------------------------------------------------------------------------
// Head: 1024 threads/tree; mean over 255 h rows -> lin0 + ReLU -> lin1 dot.
// ---------------------------------------------------------------------------
__global__ __launch_bounds__(1024) void head_wide(
    const float* __restrict__ h,
    const float* __restrict__ l0w, const float* __restrict__ l0b,
    const float* __restrict__ l1w, const float* __restrict__ l1b,
    float* __restrict__ out)
{
    __shared__ float ms[4][HH];
    __shared__ float part[4][HH];
    __shared__ float red[4];
    int b = blockIdx.x, tid = threadIdx.x;
    int j = tid & 255, g = tid >> 8;
    const float* hb = h + (size_t)b * NPT * HH;

    float a = 0.f;
    for (int i = g; i < NPT; i += 4) a += hb[(size_t)i * HH + j];
    ms[g][j] = a;
    __syncthreads();
    if (g == 0) ms[0][j] = (ms[0][j] + ms[1][j] + ms[2][j] + ms[3][j]) * (1.0f / (float)NPT);
    __syncthreads();

    const float4* L0 = (const float4*)(l0w + (size_t)j * HH);
    float y = 0.f;
    for (int k4 = 16 * g; k4 < 16 * (g + 1); ++k4) {
        float4 wv = L0[k4];
        float4 m4 = ((const float4*)ms[0])[k4];
        y += wv.x * m4.x + wv.y * m4.y + wv.z * m4.z + wv.w * m4.w;
    }
    part[g][j] = y;
    __syncthreads();

    if (g == 0) {
        float yy = part[0][j] + part[1][j] + part[2][j] + part[3][j] + l0b[j];
        yy = fmaxf(yy, 0.f);
        float v = yy * l1w[j];
        for (int off = 32; off > 0; off >>= 1) v += __shfl_down(v, off, 64);
        if ((j & 63) == 0) red[j >> 6] = v;
    }
    __syncthreads();
    if (tid == 0) out[b] = red[0] + red[1] + red[2] + red[3] + l1b[0];
}

// ---------------------------------------------------------------------------
extern "C" void kernel_launch(void* const* d_in, const int* in_sizes, int n_in,
                              void* d_out, int out_size, void* d_ws, size_t ws_size,
                              hipStream_t stream)
{
    const float* feat = (const float*)d_in[0];
    const float* Wiou = (const float*)d_in[4];
    const float* biou = (const float*)d_in[5];
    const float* Uiou = (const float*)d_in[6];
    const float* Wf   = (const float*)d_in[7];
    const float* bfv  = (const float*)d_in[8];
    const float* Uf   = (const float*)d_in[9];
    const float* l0w  = (const float*)d_in[10];
    const float* l0b  = (const float*)d_in[11];
    const float* l1w  = (const float*)d_in[12];
    const float* l1b  = (const float*)d_in[13];

    float* h = (float*)d_ws;
    float* c = h + (size_t)NTOT * HH;
    u16* Bhi = (u16*)(c + (size_t)NTOT * HH);
    u16* Blo = Bhi + 409600;

    // pack weights (every launch; ws is re-poisoned by harness)
    pack_B<<<1600, 256, 0, stream>>>(Uiou, Uf, Wiou, Wf, Bhi, Blo);

    // leaves: M=16384, NCT=10 (CSPLIT=2) -> 512*2 = 1024 blocks
    level_mfma<10, true><<<1024, 256, 0, stream>>>(feat, Bhi, Blo, biou, bfv, h, c, 127, 7);
    // t=1: M=8192, NCT=10 -> 256*2 = 512 blocks
    level_mfma<10, false><<<512, 256, 0, stream>>>(feat, Bhi, Blo, biou, bfv, h, c, 63, 6);
    // t=2..7: NCT=5 (CSPLIT=4)
    level_mfma<5, false><<<512, 256, 0, stream>>>(feat, Bhi, Blo, biou, bfv, h, c, 31, 5);
    level_mfma<5, false><<<256, 256, 0, stream>>>(feat, Bhi, Blo, biou, bfv, h, c, 15, 4);
    level_mfma<5, false><<<128, 256, 0, stream>>>(feat, Bhi, Blo, biou, bfv, h, c, 7, 3);
    level_mfma<5, false><<<64, 256, 0, stream>>>(feat, Bhi, Blo, biou, bfv, h, c, 3, 2);
    level_mfma<5, false><<<32, 256, 0, stream>>>(feat, Bhi, Blo, biou, bfv, h, c, 1, 1);
    level_mfma<5, false><<<16, 256, 0, stream>>>(feat, Bhi, Blo, biou, bfv, h, c, 0, 0);

    head_wide<<<B_TREES, 1024, 0, stream>>>(h, l0w, l0b, l1w, l1b, (float*)d_out);
}